// Round 1
// baseline (13683.212 us; speedup 1.0000x reference)
//
#include <hip/hip_runtime.h>

typedef unsigned int u32;
typedef unsigned short u16;
typedef short s8 __attribute__((ext_vector_type(8)));   // 8 x bf16 (as i16)
typedef float f4 __attribute__((ext_vector_type(4)));

#define B_SZ   1024
#define H_SZ   512
#define G4     2048
#define NSTEPS 64
#define NJS    64

// ws layout (bytes)
#define WS_XE     0u          // [64][1024][16] bf16           = 2097152
#define WS_W0P    2097152u    // [2048][544] bf16              = 2228224
#define WS_W1P    4325376u    // [2048][1024] bf16             = 4194304
#define WS_H0S    8519680u    // [2][1024][512] bf16           = 2097152
#define WS_H1S    10616832u   // [2][1024][512] bf16           = 2097152
#define WS_YPART  12713984u   // [1024][64] f32                = 262144
#define WS_FLAGS  12976128u   // [4][64] int                   = 1024
#define WS_NEEDED 12977152u

// LDS layout (bytes): W0 slice [32][552] bf16, W1 slice [32][1032] bf16, yrow f32[256]
#define LDS_W0_STRIDE 1104
#define LDS_W1_STRIDE 2064
#define LDS_W1_OFF    35328
#define LDS_YROW_OFF  101376
#define LDS_TOTAL     102400

__device__ __forceinline__ float bf2f(short s) {
  u32 u = ((u32)(u16)s) << 16; float f; __builtin_memcpy(&f, &u, 4); return f;
}
__device__ __forceinline__ short f2bf(float f) {
  u32 u; __builtin_memcpy(&u, &f, 4);
  u = (u + 0x7fffu + ((u >> 16) & 1u)) >> 16; return (short)u;
}
__device__ __forceinline__ float sigm(float x) { return 1.f / (1.f + __expf(-x)); }
__device__ __forceinline__ float tanh_(float x) {
  float ax = fminf(fabsf(x), 15.f);
  float e = __expf(2.f * ax);
  float r = (e - 1.f) / (e + 1.f);
  return x < 0.f ? -r : r;
}

// ---------------- prep kernels ----------------
__global__ void prep_pack(const float* __restrict__ Wih0, const float* __restrict__ Whh0,
                          const float* __restrict__ Wih1, const float* __restrict__ Whh1,
                          u16* __restrict__ W0p, u16* __restrict__ W1p) {
  int stride = gridDim.x * blockDim.x;
  int i0 = blockIdx.x * blockDim.x + threadIdx.x;
  for (int idx = i0; idx < G4 * 544; idx += stride) {
    int n = idx / 544, k = idx - n * 544;
    float v = 0.f;
    if (k < 32) { if (k < 9) v = Wih0[n * 9 + k]; }
    else v = Whh0[n * 512 + (k - 32)];
    W0p[idx] = (u16)f2bf(v);
  }
  for (int idx = i0; idx < G4 * 1024; idx += stride) {
    int n = idx >> 10, k = idx & 1023;
    float v = (k < 512) ? Wih1[n * 512 + k] : Whh1[n * 512 + (k - 512)];
    W1p[idx] = (u16)f2bf(v);
  }
}

__global__ void prep_xe(const float* __restrict__ xf, const float* __restrict__ z,
                        const float* __restrict__ Wz, const float* __restrict__ bz,
                        u16* __restrict__ xe) {
  int idx = blockIdx.x * blockDim.x + threadIdx.x;
  if (idx >= NSTEPS * B_SZ) return;
  int t = idx >> 10, b = idx & 1023;
  float zb[9];
#pragma unroll
  for (int i = 0; i < 9; i++) {
    float s = bz[i];
#pragma unroll
    for (int d = 0; d < 16; d++) s += z[b * 16 + d] * Wz[i * 16 + d];
    zb[i] = s;
  }
  __align__(16) u16 o[16];
  o[0] = (u16)f2bf(zb[0]);
#pragma unroll
  for (int e = 0; e < 8; e++) o[1 + e] = (u16)f2bf(xf[b * 512 + t * 8 + e] + zb[1 + e]);
#pragma unroll
  for (int k = 9; k < 16; k++) o[k] = 0;
  uint4* dst = (uint4*)(xe + (size_t)idx * 16);
  dst[0] = *(const uint4*)&o[0];
  dst[1] = *(const uint4*)&o[8];
}

__global__ void prep_state(const float* __restrict__ h0in, u16* __restrict__ h0s,
                           u16* __restrict__ h1s, int* __restrict__ flags) {
  int i = blockIdx.x * blockDim.x + threadIdx.x;
  if (i < B_SZ * H_SZ) {
    h0s[524288 + i] = (u16)f2bf(h0in[i]);
    h1s[524288 + i] = (u16)f2bf(h0in[524288 + i]);
  }
  if (i < 256) flags[i] = 0;
}

// ---------------- main persistent kernel ----------------
struct MainParams {
  const float* y0; const float* c0;
  const float* bih0; const float* bhh0; const float* bih1; const float* bhh1;
  const float* wproj; const float* bproj;
  const u16* xe; const u16* W0p; const u16* W1p;
  u16* h0s; u16* h1s; float* ypart; int* flags; float* out;
};

__device__ __forceinline__ f4 MFMA_(s8 a, s8 b, f4 c) {
  return __builtin_amdgcn_mfma_f32_16x16x32_bf16(a, b, c, 0, 0, 0);
}

// 16 K-chunks (K=512) : A from global rows (bf16 [1024][512]), B from LDS weight slice
__device__ __forceinline__ void gemm16(const char* __restrict__ A, int aoff0, int aoff1,
                                       const char* wb0, const char* wb1, f4 acc[4]) {
  s8 a0 = *(const s8*)(A + aoff0);
  s8 a1 = *(const s8*)(A + aoff1);
#pragma unroll
  for (int kc = 0; kc < 16; kc++) {
    s8 ca0 = a0, ca1 = a1;
    if (kc < 15) {
      a0 = *(const s8*)(A + aoff0 + (kc + 1) * 64);
      a1 = *(const s8*)(A + aoff1 + (kc + 1) * 64);
    }
    s8 b0 = *(const s8*)(wb0 + kc * 64);
    s8 b1 = *(const s8*)(wb1 + kc * 64);
    acc[0] = MFMA_(ca0, b0, acc[0]);
    acc[1] = MFMA_(ca0, b1, acc[1]);
    acc[2] = MFMA_(ca1, b0, acc[2]);
    acc[3] = MFMA_(ca1, b1, acc[3]);
  }
}

__device__ __forceinline__ void phase_barrier(int* flagc, int js, int tid, int target) {
  __threadfence();
  __syncthreads();
  if (tid == 0) __hip_atomic_fetch_add(&flagc[js], 1, __ATOMIC_RELAXED, __HIP_MEMORY_SCOPE_SYSTEM);
  if (tid < 64) {
    int spins = 0;
    while (__hip_atomic_load(&flagc[tid], __ATOMIC_RELAXED, __HIP_MEMORY_SCOPE_SYSTEM) < target) {
      __builtin_amdgcn_s_sleep(1);
      if (++spins > (1 << 20)) break;   // fail-safe: never hang
    }
  }
  __syncthreads();
  __threadfence();
}

struct LaneCtx { int mb0, grp, pp, jl, hlf; };

// epilogue: bias, lane^8 exchange (i,g <-> f,o), cell math, c-in-regs, h store (bf16)
__device__ __forceinline__ void cell_update(f4 acc[4], const float bias[2], float cr[2][2],
    u16* __restrict__ hdst, int j, const LaneCtx& L, float hval[2][2]) {
#pragma unroll
  for (int m = 0; m < 2; m++)
#pragma unroll
    for (int n = 0; n < 2; n++)
#pragma unroll
      for (int r = 0; r < 4; r++) acc[m * 2 + n][r] += bias[n];
  f4 rx[4];
#pragma unroll
  for (int q = 0; q < 4; q++)
#pragma unroll
    for (int r = 0; r < 4; r++) rx[q][r] = __shfl_xor(acc[q][r], 8);
#pragma unroll
  for (int mtl = 0; mtl < 2; mtl++) {
#pragma unroll
    for (int q = 0; q < 2; q++) {
      int r = L.hlf * 2 + q;
      float iv = L.hlf ? rx[mtl * 2 + 0][r] : acc[mtl * 2 + 0][r];
      float fv = L.hlf ? acc[mtl * 2 + 0][r] : rx[mtl * 2 + 0][r];
      float gv = L.hlf ? rx[mtl * 2 + 1][r] : acc[mtl * 2 + 1][r];
      float ov = L.hlf ? acc[mtl * 2 + 1][r] : rx[mtl * 2 + 1][r];
      float c2 = sigm(fv) * cr[mtl][q] + sigm(iv) * tanh_(gv);
      float hv = sigm(ov) * tanh_(c2);
      cr[mtl][q] = c2;
      hval[mtl][q] = hv;
      int row = L.mb0 + mtl * 16 + L.grp * 4 + r;
      hdst[row * 512 + j] = (u16)f2bf(hv);
    }
  }
}

__global__ __launch_bounds__(512, 2) void lstm_main(MainParams p) {
  extern __shared__ char lds[];
  char* ldsW0 = lds;
  char* ldsW1 = lds + LDS_W1_OFF;
  float* yrow = (float*)(lds + LDS_YROW_OFF);

  const int bx = blockIdx.x, chunk = bx >> 6, js = bx & 63;
  const int tid = threadIdx.x, lane = tid & 63, wid = tid >> 6;

  { // stage this block's weight slices into LDS (once for all 64 steps)
    int n = tid & 31, part = tid >> 5;   // 32 rows x 16 parts
    int ng = ((n >> 3) << 9) + js * 8 + (n & 7);
    const u32* s0 = (const u32*)(p.W0p + (size_t)ng * 544);
    u32* d0 = (u32*)(ldsW0 + n * LDS_W0_STRIDE);
#pragma unroll
    for (int q = 0; q < 17; q++) d0[part * 17 + q] = s0[part * 17 + q];
    const u32* s1 = (const u32*)(p.W1p + (size_t)ng * 1024);
    u32* d1 = (u32*)(ldsW1 + n * LDS_W1_STRIDE);
#pragma unroll
    for (int q = 0; q < 32; q++) d1[part * 32 + q] = s1[part * 32 + q];
  }

  LaneCtx L;
  L.grp = lane >> 4; L.pp = lane & 15; L.jl = lane & 7; L.hlf = (lane >> 3) & 1;
  L.mb0 = chunk * 256 + wid * 32;
  const int j = js * 8 + L.jl;
  const int arow0 = L.mb0 + L.pp, arow1 = L.mb0 + 16 + L.pp;
  const int aoff0 = arow0 * 1024 + L.grp * 16;   // bytes into [1024][512] bf16
  const int aoff1 = arow1 * 1024 + L.grp * 16;

  float bias0[2], bias1[2];
#pragma unroll
  for (int ntl = 0; ntl < 2; ntl++) {
    int n = ntl * 16 + L.pp;
    int ng = ((n >> 3) << 9) + js * 8 + (n & 7);
    bias0[ntl] = p.bih0[ng] + p.bhh0[ng];
    bias1[ntl] = p.bih1[ng] + p.bhh1[ng];
  }
  float wpj = p.wproj[j];
  float bpj = p.bproj[0];

  float c0r[2][2], c1r[2][2];   // persistent cell state in registers
#pragma unroll
  for (int mtl = 0; mtl < 2; mtl++)
#pragma unroll
    for (int q = 0; q < 2; q++) {
      int row = L.mb0 + mtl * 16 + L.grp * 4 + L.hlf * 2 + q;
      c0r[mtl][q] = p.c0[row * 512 + j];
      c1r[mtl][q] = p.c0[524288 + row * 512 + j];
    }

  int* flagc = p.flags + chunk * 64;
  const char* wb00 = ldsW0 + L.pp * LDS_W0_STRIDE + L.grp * 16;
  const char* wb01 = ldsW0 + (16 + L.pp) * LDS_W0_STRIDE + L.grp * 16;
  const char* wb10 = ldsW1 + L.pp * LDS_W1_STRIDE + L.grp * 16;
  const char* wb11 = ldsW1 + (16 + L.pp) * LDS_W1_STRIDE + L.grp * 16;

  __syncthreads();

  for (int t = 0; t < NSTEPS; t++) {
    // ---- prev_y for this chunk (fixed-order reduction of ypart) ----
    if (tid < 256) {
      int row = chunk * 256 + tid;
      float y;
      if (t == 0) y = p.y0[row];
      else {
        float s = bpj;
        const float4* yp = (const float4*)(p.ypart + row * 64);
#pragma unroll
        for (int q = 0; q < 16; q++) { float4 v = yp[q]; s += v.x + v.y + v.z + v.w; }
        y = s;
        if (js == 0) p.out[row * 64 + (t - 1)] = y;
      }
      yrow[tid] = y;
    }
    __syncthreads();

    u16* h0cur = p.h0s + (size_t)(t & 1) * 524288;
    const char* h0prev = (const char*)(p.h0s + (size_t)((t + 1) & 1) * 524288);
    u16* h1cur = p.h1s + (size_t)(t & 1) * 524288;
    const char* h1prev = (const char*)(p.h1s + (size_t)((t + 1) & 1) * 524288);

    // ================= layer 0 =================
    {
      f4 acc[4] = {{0.f,0.f,0.f,0.f},{0.f,0.f,0.f,0.f},{0.f,0.f,0.f,0.f},{0.f,0.f,0.f,0.f}};
      { // K-chunk 0: in_t part ([prev_y, exo]+z_bias, K padded to 32)
        s8 a0 = {0,0,0,0,0,0,0,0}, a1 = {0,0,0,0,0,0,0,0};
        if (L.grp < 2) {
          const char* xb = (const char*)p.xe + (size_t)t * 1024 * 32;
          a0 = *(const s8*)(xb + arow0 * 32 + L.grp * 16);
          a1 = *(const s8*)(xb + arow1 * 32 + L.grp * 16);
          if (L.grp == 0) {
            float ya = yrow[wid * 32 + L.pp];
            float yb = yrow[wid * 32 + 16 + L.pp];
            a0[0] = f2bf(bf2f(a0[0]) + ya);
            a1[0] = f2bf(bf2f(a1[0]) + yb);
          }
        }
        s8 b0 = *(const s8*)(wb00);
        s8 b1 = *(const s8*)(wb01);
        acc[0] = MFMA_(a0, b0, acc[0]);
        acc[1] = MFMA_(a0, b1, acc[1]);
        acc[2] = MFMA_(a1, b0, acc[2]);
        acc[3] = MFMA_(a1, b1, acc[3]);
      }
      gemm16(h0prev, aoff0, aoff1, wb00 + 64, wb01 + 64, acc);   // h0 @ W_hh0^T
      float hval[2][2];
      cell_update(acc, bias0, c0r, h0cur, j, L, hval);
    }
    phase_barrier(flagc, js, tid, 2 * t + 1);

    // ================= layer 1 =================
    {
      f4 acc[4] = {{0.f,0.f,0.f,0.f},{0.f,0.f,0.f,0.f},{0.f,0.f,0.f,0.f},{0.f,0.f,0.f,0.f}};
      gemm16((const char*)h0cur, aoff0, aoff1, wb10, wb11, acc);          // h0n @ W_ih1^T
      gemm16(h1prev, aoff0, aoff1, wb10 + 1024, wb11 + 1024, acc);        // h1  @ W_hh1^T
      float hval[2][2];
      cell_update(acc, bias1, c1r, h1cur, j, L, hval);
      // proj partials over this block's 8 j's
#pragma unroll
      for (int mtl = 0; mtl < 2; mtl++)
#pragma unroll
        for (int q = 0; q < 2; q++) {
          float s = hval[mtl][q] * wpj;
          s += __shfl_xor(s, 1);
          s += __shfl_xor(s, 2);
          s += __shfl_xor(s, 4);
          if (L.jl == 0) {
            int row = L.mb0 + mtl * 16 + L.grp * 4 + L.hlf * 2 + q;
            p.ypart[row * 64 + js] = s;
          }
        }
    }
    phase_barrier(flagc, js, tid, 2 * t + 2);
  }

  // final step's yhat
  if (js == 0 && tid < 256) {
    int row = chunk * 256 + tid;
    float s = bpj;
    const float4* yp = (const float4*)(p.ypart + row * 64);
#pragma unroll
    for (int q = 0; q < 16; q++) { float4 v = yp[q]; s += v.x + v.y + v.z + v.w; }
    p.out[row * 64 + 63] = s;
  }
}

extern "C" void kernel_launch(void* const* d_in, const int* in_sizes, int n_in,
                              void* d_out, int out_size, void* d_ws, size_t ws_size,
                              hipStream_t stream) {
  const float* y0   = (const float*)d_in[0];
  const float* xf   = (const float*)d_in[1];
  const float* h0   = (const float*)d_in[2];
  const float* c0   = (const float*)d_in[3];
  const float* z    = (const float*)d_in[4];
  const float* Wih0 = (const float*)d_in[5];
  const float* Whh0 = (const float*)d_in[6];
  const float* bih0 = (const float*)d_in[7];
  const float* bhh0 = (const float*)d_in[8];
  const float* Wih1 = (const float*)d_in[9];
  const float* Whh1 = (const float*)d_in[10];
  const float* bih1 = (const float*)d_in[11];
  const float* bhh1 = (const float*)d_in[12];
  const float* Wpr  = (const float*)d_in[13];
  const float* bpr  = (const float*)d_in[14];
  const float* Wz   = (const float*)d_in[15];
  const float* bz   = (const float*)d_in[16];

  if (ws_size < WS_NEEDED) return;
  char* ws = (char*)d_ws;
  u16* xe    = (u16*)(ws + WS_XE);
  u16* W0p   = (u16*)(ws + WS_W0P);
  u16* W1p   = (u16*)(ws + WS_W1P);
  u16* h0s   = (u16*)(ws + WS_H0S);
  u16* h1s   = (u16*)(ws + WS_H1S);
  float* ypart = (float*)(ws + WS_YPART);
  int* flags = (int*)(ws + WS_FLAGS);

  prep_pack<<<1024, 256, 0, stream>>>(Wih0, Whh0, Wih1, Whh1, W0p, W1p);
  prep_xe<<<256, 256, 0, stream>>>(xf, z, Wz, bz, xe);
  prep_state<<<2048, 256, 0, stream>>>(h0, h0s, h1s, flags);

  MainParams prm;
  prm.y0 = y0; prm.c0 = c0;
  prm.bih0 = bih0; prm.bhh0 = bhh0; prm.bih1 = bih1; prm.bhh1 = bhh1;
  prm.wproj = Wpr; prm.bproj = bpr;
  prm.xe = xe; prm.W0p = W0p; prm.W1p = W1p;
  prm.h0s = h0s; prm.h1s = h1s; prm.ypart = ypart; prm.flags = flags;
  prm.out = (float*)d_out;

  hipFuncSetAttribute((const void*)lstm_main, hipFuncAttributeMaxDynamicSharedMemorySize, LDS_TOTAL);
  void* args[] = { &prm };
  hipLaunchCooperativeKernel((void*)lstm_main, dim3(256), dim3(512), args, LDS_TOTAL, stream);
}

// Round 2
// 3248.962 us; speedup vs baseline: 4.2116x; 4.2116x over previous
//
#include <hip/hip_runtime.h>

typedef unsigned int u32;
typedef unsigned short u16;
typedef unsigned long long u64;
typedef short s8 __attribute__((ext_vector_type(8)));   // 8 x bf16 (as i16)
typedef float f4 __attribute__((ext_vector_type(4)));

#define B_SZ   1024
#define H_SZ   512
#define G4     2048
#define NSTEPS 64

// ws layout (bytes)
#define WS_XE     0u          // [64][1024][16] bf16           = 2097152
#define WS_W0P    2097152u    // [2048][544] bf16              = 2228224
#define WS_W1P    4325376u    // [2048][1024] bf16             = 4194304
#define WS_H0S    8519680u    // [2][1024][512] bf16           = 2097152
#define WS_H1S    10616832u   // [2][1024][512] bf16           = 2097152
#define WS_YPART  12713984u   // [1024][64] f32                = 262144
#define WS_FLAGS  12976128u   // [4][64] u32                   = 1024
#define WS_NEEDED 12977152u

// LDS layout (bytes)
#define LDS_W0_STRIDE 1104     // 552 bf16
#define LDS_W1_STRIDE 2064     // 1032 bf16
#define LDS_W1_OFF    35328
#define LDS_YROW_OFF  101376   // f32[256]
#define LDS_HST_OFF   102400   // u16[256][8]
#define LDS_TOTAL     106496

__device__ __forceinline__ float bf2f(short s) {
  u32 u = ((u32)(u16)s) << 16; float f; __builtin_memcpy(&f, &u, 4); return f;
}
__device__ __forceinline__ short f2bf(float f) {
  u32 u; __builtin_memcpy(&u, &f, 4);
  u = (u + 0x7fffu + ((u >> 16) & 1u)) >> 16; return (short)u;
}
__device__ __forceinline__ float sigm(float x) { return 1.f / (1.f + __expf(-x)); }
__device__ __forceinline__ float tanh_(float x) {
  float ax = fminf(fabsf(x), 15.f);
  float e = __expf(2.f * ax);
  float r = (e - 1.f) / (e + 1.f);
  return x < 0.f ? -r : r;
}

// agent-scope relaxed atomics: L2-bypassing, cross-XCD coherent, NO fences needed
__device__ __forceinline__ u64 ald(const u64* p) {
  return __hip_atomic_load(p, __ATOMIC_RELAXED, __HIP_MEMORY_SCOPE_AGENT);
}
__device__ __forceinline__ void ast(u64* p, u64 v) {
  __hip_atomic_store(p, v, __ATOMIC_RELAXED, __HIP_MEMORY_SCOPE_AGENT);
}
__device__ __forceinline__ u32 ald32(const u32* p) {
  return __hip_atomic_load(p, __ATOMIC_RELAXED, __HIP_MEMORY_SCOPE_AGENT);
}
__device__ __forceinline__ void ast32(u32* p, u32 v) {
  __hip_atomic_store(p, v, __ATOMIC_RELAXED, __HIP_MEMORY_SCOPE_AGENT);
}

// ---------------- prep kernels ----------------
__global__ void prep_pack(const float* __restrict__ Wih0, const float* __restrict__ Whh0,
                          const float* __restrict__ Wih1, const float* __restrict__ Whh1,
                          u16* __restrict__ W0p, u16* __restrict__ W1p) {
  int stride = gridDim.x * blockDim.x;
  int i0 = blockIdx.x * blockDim.x + threadIdx.x;
  for (int idx = i0; idx < G4 * 544; idx += stride) {
    int n = idx / 544, k = idx - n * 544;
    float v = 0.f;
    if (k < 32) { if (k < 9) v = Wih0[n * 9 + k]; }
    else v = Whh0[n * 512 + (k - 32)];
    W0p[idx] = (u16)f2bf(v);
  }
  for (int idx = i0; idx < G4 * 1024; idx += stride) {
    int n = idx >> 10, k = idx & 1023;
    float v = (k < 512) ? Wih1[n * 512 + k] : Whh1[n * 512 + (k - 512)];
    W1p[idx] = (u16)f2bf(v);
  }
}

__global__ void prep_xe(const float* __restrict__ xf, const float* __restrict__ z,
                        const float* __restrict__ Wz, const float* __restrict__ bz,
                        u16* __restrict__ xe) {
  int idx = blockIdx.x * blockDim.x + threadIdx.x;
  if (idx >= NSTEPS * B_SZ) return;
  int t = idx >> 10, b = idx & 1023;
  float zb[9];
#pragma unroll
  for (int i = 0; i < 9; i++) {
    float s = bz[i];
#pragma unroll
    for (int d = 0; d < 16; d++) s += z[b * 16 + d] * Wz[i * 16 + d];
    zb[i] = s;
  }
  __align__(16) u16 o[16];
  o[0] = (u16)f2bf(zb[0]);
#pragma unroll
  for (int e = 0; e < 8; e++) o[1 + e] = (u16)f2bf(xf[b * 512 + t * 8 + e] + zb[1 + e]);
#pragma unroll
  for (int k = 9; k < 16; k++) o[k] = 0;
  uint4* dst = (uint4*)(xe + (size_t)idx * 16);
  dst[0] = *(const uint4*)&o[0];
  dst[1] = *(const uint4*)&o[8];
}

__global__ void prep_state(const float* __restrict__ h0in, u16* __restrict__ h0s,
                           u16* __restrict__ h1s, u32* __restrict__ flags) {
  int i = blockIdx.x * blockDim.x + threadIdx.x;
  if (i < B_SZ * H_SZ) {
    h0s[524288 + i] = (u16)f2bf(h0in[i]);
    h1s[524288 + i] = (u16)f2bf(h0in[524288 + i]);
  }
  if (i < 256) flags[i] = 0;
}

// ---------------- main persistent kernel ----------------
struct MainParams {
  const float* y0; const float* c0;
  const float* bih0; const float* bhh0; const float* bih1; const float* bhh1;
  const float* wproj; const float* bproj;
  const u16* xe; const u16* W0p; const u16* W1p;
  u64* h0u; u64* h1u; float* ypart; u32* flags; float* out;
};

__device__ __forceinline__ f4 MFMA_(s8 a, s8 b, f4 c) {
  return __builtin_amdgcn_mfma_f32_16x16x32_bf16(a, b, c, 0, 0, 0);
}

union uab { u64 q[2]; s8 v; };
union uf2 { u64 q; float f[2]; };

// K=512 gemm, A via agent-atomic u64 loads (batched 64 loads in flight), 2 B-cols
__device__ __forceinline__ void gemmK512_2(const u64* hb, int au0, int au1,
    const char* b0p, const char* b1p, f4 acc[4]) {
  u64 qa[16][2][2];
#pragma unroll
  for (int kc = 0; kc < 16; kc++) {
    qa[kc][0][0] = ald(hb + au0 + kc * 8);
    qa[kc][0][1] = ald(hb + au0 + kc * 8 + 1);
    qa[kc][1][0] = ald(hb + au1 + kc * 8);
    qa[kc][1][1] = ald(hb + au1 + kc * 8 + 1);
  }
#pragma unroll
  for (int kc = 0; kc < 16; kc++) {
    s8 b0 = *(const s8*)(b0p + kc * 64);
    s8 b1 = *(const s8*)(b1p + kc * 64);
    uab a0; a0.q[0] = qa[kc][0][0]; a0.q[1] = qa[kc][0][1];
    uab a1; a1.q[0] = qa[kc][1][0]; a1.q[1] = qa[kc][1][1];
    acc[0] = MFMA_(a0.v, b0, acc[0]);
    acc[1] = MFMA_(a0.v, b1, acc[1]);
    acc[2] = MFMA_(a1.v, b0, acc[2]);
    acc[3] = MFMA_(a1.v, b1, acc[3]);
  }
}

// K=512 gemm feeding TWO acc sets (layer1 gates + next-step layer0 h-part), shared A
__device__ __forceinline__ void gemmK512_4(const u64* hb, int au0, int au1,
    const char* b10p, const char* b11p, f4 acc1[4],
    const char* b00p, const char* b01p, f4 acc0[4]) {
  u64 qa[16][2][2];
#pragma unroll
  for (int kc = 0; kc < 16; kc++) {
    qa[kc][0][0] = ald(hb + au0 + kc * 8);
    qa[kc][0][1] = ald(hb + au0 + kc * 8 + 1);
    qa[kc][1][0] = ald(hb + au1 + kc * 8);
    qa[kc][1][1] = ald(hb + au1 + kc * 8 + 1);
  }
#pragma unroll
  for (int kc = 0; kc < 16; kc++) {
    s8 b10 = *(const s8*)(b10p + kc * 64);
    s8 b11 = *(const s8*)(b11p + kc * 64);
    s8 b00 = *(const s8*)(b00p + kc * 64);
    s8 b01 = *(const s8*)(b01p + kc * 64);
    uab a0; a0.q[0] = qa[kc][0][0]; a0.q[1] = qa[kc][0][1];
    uab a1; a1.q[0] = qa[kc][1][0]; a1.q[1] = qa[kc][1][1];
    acc1[0] = MFMA_(a0.v, b10, acc1[0]);
    acc1[1] = MFMA_(a0.v, b11, acc1[1]);
    acc1[2] = MFMA_(a1.v, b10, acc1[2]);
    acc1[3] = MFMA_(a1.v, b11, acc1[3]);
    acc0[0] = MFMA_(a0.v, b00, acc0[0]);
    acc0[1] = MFMA_(a0.v, b01, acc0[1]);
    acc0[2] = MFMA_(a1.v, b00, acc0[2]);
    acc0[3] = MFMA_(a1.v, b01, acc0[3]);
  }
}

// arrival: per-wave vmcnt drain -> one relaxed flag store -> 1-wave poll of 64 slots
__device__ __forceinline__ void barrier_wait(u32* slots, int js, int tid, u32 target) {
  asm volatile("s_waitcnt vmcnt(0)" ::: "memory");
  __syncthreads();
  if (tid == 0) ast32(&slots[js], target);
  if (tid < 64) {
    int spins = 0;
    while (ald32(&slots[tid]) < target) {
      __builtin_amdgcn_s_sleep(8);
      if (++spins > (1 << 16)) break;   // fail-safe: never hang
    }
  }
  __syncthreads();
}

struct LaneCtx { int mb0, grp, pp, jl, hlf; };

// bias, lane^8 gate exchange (i,g <-> f,o), cell math, write h (bf16) to LDS stage
__device__ __forceinline__ void cell_update(f4 acc[4], const float bias[2], float cr[2][2],
    u16* __restrict__ hst, int lbase, const LaneCtx& L, float hval[2][2]) {
#pragma unroll
  for (int m = 0; m < 2; m++)
#pragma unroll
    for (int n = 0; n < 2; n++)
#pragma unroll
      for (int r = 0; r < 4; r++) acc[m * 2 + n][r] += bias[n];
  f4 rx[4];
#pragma unroll
  for (int q = 0; q < 4; q++)
#pragma unroll
    for (int r = 0; r < 4; r++) rx[q][r] = __shfl_xor(acc[q][r], 8);
#pragma unroll
  for (int mtl = 0; mtl < 2; mtl++) {
#pragma unroll
    for (int q = 0; q < 2; q++) {
      int r = L.hlf * 2 + q;
      float iv = L.hlf ? rx[mtl * 2 + 0][r] : acc[mtl * 2 + 0][r];
      float fv = L.hlf ? acc[mtl * 2 + 0][r] : rx[mtl * 2 + 0][r];
      float gv = L.hlf ? rx[mtl * 2 + 1][r] : acc[mtl * 2 + 1][r];
      float ov = L.hlf ? acc[mtl * 2 + 1][r] : rx[mtl * 2 + 1][r];
      float c2 = sigm(fv) * cr[mtl][q] + sigm(iv) * tanh_(gv);
      float hv = sigm(ov) * tanh_(c2);
      cr[mtl][q] = c2;
      hval[mtl][q] = hv;
      int lrow = lbase + mtl * 16 + L.grp * 4 + r;
      hst[lrow * 8 + L.jl] = (u16)f2bf(hv);
    }
  }
}

__global__ __launch_bounds__(512, 2) void lstm_main(MainParams p) {
  extern __shared__ char lds[];
  char* ldsW0 = lds;
  char* ldsW1 = lds + LDS_W1_OFF;
  float* yrow = (float*)(lds + LDS_YROW_OFF);
  u16* hst = (u16*)(lds + LDS_HST_OFF);

  const int bx = blockIdx.x, chunk = bx >> 6, js = bx & 63;
  const int tid = threadIdx.x, lane = tid & 63, wid = tid >> 6;

  { // stage weight slices into LDS once (fence-immune for the whole recurrence)
    int n = tid & 31, part = tid >> 5;
    int ng = ((n >> 3) << 9) + js * 8 + (n & 7);
    const u32* s0 = (const u32*)(p.W0p + (size_t)ng * 544);
    u32* d0 = (u32*)(ldsW0 + n * LDS_W0_STRIDE);
#pragma unroll
    for (int q = 0; q < 17; q++) d0[part * 17 + q] = s0[part * 17 + q];
    const u32* s1 = (const u32*)(p.W1p + (size_t)ng * 1024);
    u32* d1 = (u32*)(ldsW1 + n * LDS_W1_STRIDE);
#pragma unroll
    for (int q = 0; q < 32; q++) d1[part * 32 + q] = s1[part * 32 + q];
  }

  LaneCtx L;
  L.grp = lane >> 4; L.pp = lane & 15; L.jl = lane & 7; L.hlf = (lane >> 3) & 1;
  L.mb0 = chunk * 256 + wid * 32;
  const int lbase = wid * 32;
  const int j = js * 8 + L.jl;
  const int arow0 = L.mb0 + L.pp, arow1 = L.mb0 + 16 + L.pp;
  const int au0 = arow0 * 128 + L.grp * 2;   // u64 index into [1024][512] bf16
  const int au1 = arow1 * 128 + L.grp * 2;

  float bias0[2], bias1[2];
#pragma unroll
  for (int ntl = 0; ntl < 2; ntl++) {
    int n = ntl * 16 + L.pp;
    int ng = ((n >> 3) << 9) + js * 8 + (n & 7);
    bias0[ntl] = p.bih0[ng] + p.bhh0[ng];
    bias1[ntl] = p.bih1[ng] + p.bhh1[ng];
  }
  float wpj = p.wproj[j];
  float bpj = p.bproj[0];

  float c0r[2][2], c1r[2][2];
#pragma unroll
  for (int mtl = 0; mtl < 2; mtl++)
#pragma unroll
    for (int q = 0; q < 2; q++) {
      int row = L.mb0 + mtl * 16 + L.grp * 4 + L.hlf * 2 + q;
      c0r[mtl][q] = p.c0[row * 512 + j];
      c1r[mtl][q] = p.c0[524288 + row * 512 + j];
    }

  u32* flagc = p.flags + chunk * 64;
  const char* wb00 = ldsW0 + L.pp * LDS_W0_STRIDE + L.grp * 16;
  const char* wb01 = ldsW0 + (16 + L.pp) * LDS_W0_STRIDE + L.grp * 16;
  const char* wb10 = ldsW1 + L.pp * LDS_W1_STRIDE + L.grp * 16;
  const char* wb11 = ldsW1 + (16 + L.pp) * LDS_W1_STRIDE + L.grp * 16;

  __syncthreads();

  // prologue: layer-0 h-part for t=0 from initial h0 (buffer 1)
  f4 acc0c[4] = {{0,0,0,0},{0,0,0,0},{0,0,0,0},{0,0,0,0}};
  gemmK512_2(p.h0u + 131072, au0, au1, wb00 + 64, wb01 + 64, acc0c);

  for (int t = 0; t < NSTEPS; t++) {
    // ================= phase 1: y-reduce + rank-32 input gemm + cell0 =================
    if (tid < 256) {
      int row = chunk * 256 + tid;
      float y;
      if (t == 0) y = p.y0[row];
      else {
        float s = bpj;
        const u64* yp = (const u64*)(p.ypart + row * 64);
#pragma unroll
        for (int q = 0; q < 32; q++) { uf2 w; w.q = ald(yp + q); s += w.f[0] + w.f[1]; }
        y = s;
        if (js == 0) p.out[row * 64 + (t - 1)] = y;
      }
      yrow[tid] = y;
    }
    __syncthreads();

    { // K-chunk 0 of layer 0: [prev_y, exo]+z_bias (K padded to 32)
      s8 a0 = {0,0,0,0,0,0,0,0}, a1 = {0,0,0,0,0,0,0,0};
      if (L.grp < 2) {
        const char* xb = (const char*)p.xe + (size_t)t * 32768;
        a0 = *(const s8*)(xb + arow0 * 32 + L.grp * 16);
        a1 = *(const s8*)(xb + arow1 * 32 + L.grp * 16);
        if (L.grp == 0) {
          float ya = yrow[wid * 32 + L.pp];
          float yb = yrow[wid * 32 + 16 + L.pp];
          a0[0] = f2bf(bf2f(a0[0]) + ya);
          a1[0] = f2bf(bf2f(a1[0]) + yb);
        }
      }
      s8 b0 = *(const s8*)(wb00);
      s8 b1 = *(const s8*)(wb01);
      acc0c[0] = MFMA_(a0, b0, acc0c[0]);
      acc0c[1] = MFMA_(a0, b1, acc0c[1]);
      acc0c[2] = MFMA_(a1, b0, acc0c[2]);
      acc0c[3] = MFMA_(a1, b1, acc0c[3]);
    }
    float hdum[2][2];
    cell_update(acc0c, bias0, c0r, hst, lbase, L, hdum);
    __syncthreads();
    {
      u64* h0cur = p.h0u + (size_t)(t & 1) * 131072;
      if (tid < 256) {
        const u64* src = (const u64*)&hst[tid * 8];
        u64* dst = h0cur + (chunk * 256 + tid) * 128 + js * 2;
        ast(dst, src[0]);
        ast(dst + 1, src[1]);
      }
    }
    barrier_wait(flagc, js, tid, (u32)(2 * t + 1));

    // ================= phase 2: layer1 + next-step layer0 h-part =================
    {
      const u64* h0cur = p.h0u + (size_t)(t & 1) * 131072;
      const u64* h1prev = p.h1u + (size_t)((t + 1) & 1) * 131072;
      f4 acc1[4] = {{0,0,0,0},{0,0,0,0},{0,0,0,0},{0,0,0,0}};
#pragma unroll
      for (int q = 0; q < 4; q++) acc0c[q] = (f4){0, 0, 0, 0};
      // h0cur feeds BOTH W_ih1 (layer1) and W_hh0 (next step's layer0): load A once
      gemmK512_4(h0cur, au0, au1, wb10, wb11, acc1, wb00 + 64, wb01 + 64, acc0c);
      gemmK512_2(h1prev, au0, au1, wb10 + 1024, wb11 + 1024, acc1);   // h1 @ W_hh1^T

      float hval[2][2];
      cell_update(acc1, bias1, c1r, hst, lbase, L, hval);

      // proj partials over this block's 8 j's
#pragma unroll
      for (int mtl = 0; mtl < 2; mtl++)
#pragma unroll
        for (int q = 0; q < 2; q++) {
          float s = hval[mtl][q] * wpj;
          s += __shfl_xor(s, 1);
          s += __shfl_xor(s, 2);
          s += __shfl_xor(s, 4);
          if (L.jl == 0) {
            int row = L.mb0 + mtl * 16 + L.grp * 4 + L.hlf * 2 + q;
            ast32((u32*)&p.ypart[row * 64 + js], __float_as_uint(s));
          }
        }
      __syncthreads();
      u64* h1cur = p.h1u + (size_t)(t & 1) * 131072;
      if (tid < 256) {
        const u64* src = (const u64*)&hst[tid * 8];
        u64* dst = h1cur + (chunk * 256 + tid) * 128 + js * 2;
        ast(dst, src[0]);
        ast(dst + 1, src[1]);
      }
    }
    barrier_wait(flagc, js, tid, (u32)(2 * t + 2));
  }

  // final step's yhat
  if (js == 0 && tid < 256) {
    int row = chunk * 256 + tid;
    float s = bpj;
    const u64* yp = (const u64*)(p.ypart + row * 64);
#pragma unroll
    for (int q = 0; q < 32; q++) { uf2 w; w.q = ald(yp + q); s += w.f[0] + w.f[1]; }
    p.out[row * 64 + 63] = s;
  }
}

extern "C" void kernel_launch(void* const* d_in, const int* in_sizes, int n_in,
                              void* d_out, int out_size, void* d_ws, size_t ws_size,
                              hipStream_t stream) {
  const float* y0   = (const float*)d_in[0];
  const float* xf   = (const float*)d_in[1];
  const float* h0   = (const float*)d_in[2];
  const float* c0   = (const float*)d_in[3];
  const float* z    = (const float*)d_in[4];
  const float* Wih0 = (const float*)d_in[5];
  const float* Whh0 = (const float*)d_in[6];
  const float* bih0 = (const float*)d_in[7];
  const float* bhh0 = (const float*)d_in[8];
  const float* Wih1 = (const float*)d_in[9];
  const float* Whh1 = (const float*)d_in[10];
  const float* bih1 = (const float*)d_in[11];
  const float* bhh1 = (const float*)d_in[12];
  const float* Wpr  = (const float*)d_in[13];
  const float* bpr  = (const float*)d_in[14];
  const float* Wz   = (const float*)d_in[15];
  const float* bz   = (const float*)d_in[16];

  if (ws_size < WS_NEEDED) return;
  char* ws = (char*)d_ws;
  u16* xe    = (u16*)(ws + WS_XE);
  u16* W0p   = (u16*)(ws + WS_W0P);
  u16* W1p   = (u16*)(ws + WS_W1P);
  u64* h0u   = (u64*)(ws + WS_H0S);
  u64* h1u   = (u64*)(ws + WS_H1S);
  float* ypart = (float*)(ws + WS_YPART);
  u32* flags = (u32*)(ws + WS_FLAGS);

  prep_pack<<<1024, 256, 0, stream>>>(Wih0, Whh0, Wih1, Whh1, W0p, W1p);
  prep_xe<<<256, 256, 0, stream>>>(xf, z, Wz, bz, xe);
  prep_state<<<2048, 256, 0, stream>>>(h0, (u16*)h0u, (u16*)h1u, flags);

  MainParams prm;
  prm.y0 = y0; prm.c0 = c0;
  prm.bih0 = bih0; prm.bhh0 = bhh0; prm.bih1 = bih1; prm.bhh1 = bhh1;
  prm.wproj = Wpr; prm.bproj = bpr;
  prm.xe = xe; prm.W0p = W0p; prm.W1p = W1p;
  prm.h0u = h0u; prm.h1u = h1u; prm.ypart = ypart; prm.flags = flags;
  prm.out = (float*)d_out;

  hipFuncSetAttribute((const void*)lstm_main, hipFuncAttributeMaxDynamicSharedMemorySize, LDS_TOTAL);
  void* args[] = { &prm };
  hipLaunchCooperativeKernel((void*)lstm_main, dim3(256), dim3(512), args, LDS_TOTAL, stream);
}

// Round 4
// 2145.849 us; speedup vs baseline: 6.3766x; 1.5141x over previous
//
#include <hip/hip_runtime.h>

typedef unsigned int u32;
typedef unsigned short u16;
typedef unsigned long long u64;
typedef short s8 __attribute__((ext_vector_type(8)));   // 8 x bf16 (as i16)
typedef float f4 __attribute__((ext_vector_type(4)));
typedef u32 v4 __attribute__((ext_vector_type(4)));     // 16B asm load payload

#define B_SZ   1024
#define H_SZ   512
#define G4     2048
#define NSTEPS 64

// ws layout (bytes)
#define WS_XE     0u          // [64][1024][16] bf16           = 2097152
#define WS_W0P    2097152u    // [2048][544] bf16              = 2228224
#define WS_W1P    4325376u    // [2048][1024] bf16             = 4194304
#define WS_H0S    8519680u    // [2][1024][512] bf16           = 2097152
#define WS_H1S    10616832u   // [2][1024][512] bf16           = 2097152
#define WS_YPART  12713984u   // [1024][64] f32                = 262144
#define WS_FLAGS  12976128u   // [4][64] u32                   = 1024
#define WS_NEEDED 12977152u

// LDS layout (bytes)
#define LDS_W0_STRIDE 1104     // 552 bf16
#define LDS_W1_STRIDE 2064     // 1032 bf16
#define LDS_W1_OFF    35328
#define LDS_YROW_OFF  101376   // f32[256]   -> ends 102400
#define LDS_HST_OFF   102400   // u16[256][8]-> ends 106496
#define LDS_PSUM_OFF  106496   // f32[512]   -> ends 108544
#define LDS_TOTAL     108544

__device__ __forceinline__ float bf2f(short s) {
  u32 u = ((u32)(u16)s) << 16; float f; __builtin_memcpy(&f, &u, 4); return f;
}
__device__ __forceinline__ short f2bf(float f) {
  u32 u; __builtin_memcpy(&u, &f, 4);
  u = (u + 0x7fffu + ((u >> 16) & 1u)) >> 16; return (short)u;
}
__device__ __forceinline__ float sigm(float x) { return 1.f / (1.f + __expf(-x)); }
__device__ __forceinline__ float tanh_(float x) {
  float ax = fminf(fabsf(x), 15.f);
  float e = __expf(2.f * ax);
  float r = (e - 1.f) / (e + 1.f);
  return x < 0.f ? -r : r;
}

// agent-scope relaxed atomics (flags, stores, prologue loads)
__device__ __forceinline__ u64 ald(const u64* p) {
  return __hip_atomic_load(p, __ATOMIC_RELAXED, __HIP_MEMORY_SCOPE_AGENT);
}
__device__ __forceinline__ void ast(u64* p, u64 v) {
  __hip_atomic_store(p, v, __ATOMIC_RELAXED, __HIP_MEMORY_SCOPE_AGENT);
}
__device__ __forceinline__ u32 ald32(const u32* p) {
  return __hip_atomic_load(p, __ATOMIC_RELAXED, __HIP_MEMORY_SCOPE_AGENT);
}
__device__ __forceinline__ void ast32(u32* p, u32 v) {
  __hip_atomic_store(p, v, __ATOMIC_RELAXED, __HIP_MEMORY_SCOPE_AGENT);
}

// device-scope 16B load; result is async until a WAITV.
#define LOADX4(dst, ptr, IMM) \
  asm volatile("global_load_dwordx4 %0, %1, off offset:" #IMM " sc1" : "=v"(dst) : "v"(ptr))
#define WAITV(N) do { \
  asm volatile("s_waitcnt vmcnt(" #N ")" ::: "memory"); \
  __builtin_amdgcn_sched_barrier(0); } while (0)

// issue one 8-load group: rows (p0,p1), 4 consecutive 64B k-chunks
#define IS8(r0,r1,r2,r3,r4,r5,r6,r7,p0,p1,O0,O1,O2,O3) do { \
  LOADX4(r0, p0, O0); LOADX4(r1, p1, O0); \
  LOADX4(r2, p0, O1); LOADX4(r3, p1, O1); \
  LOADX4(r4, p0, O2); LOADX4(r5, p1, O2); \
  LOADX4(r6, p0, O3); LOADX4(r7, p1, O3); } while (0)

union vv { v4 u; s8 s; };
__device__ __forceinline__ s8 as_s8(v4 x) { vv t; t.u = x; return t.s; }
union uab { u64 q[2]; s8 v; };
union uf2 { u64 q; float f[2]; };
union vf4 { v4 u; float f[4]; };

// ---------------- prep kernels ----------------
__global__ void prep_pack(const float* __restrict__ Wih0, const float* __restrict__ Whh0,
                          const float* __restrict__ Wih1, const float* __restrict__ Whh1,
                          u16* __restrict__ W0p, u16* __restrict__ W1p) {
  int stride = gridDim.x * blockDim.x;
  int i0 = blockIdx.x * blockDim.x + threadIdx.x;
  for (int idx = i0; idx < G4 * 544; idx += stride) {
    int n = idx / 544, k = idx - n * 544;
    float v = 0.f;
    if (k < 32) { if (k < 9) v = Wih0[n * 9 + k]; }
    else v = Whh0[n * 512 + (k - 32)];
    W0p[idx] = (u16)f2bf(v);
  }
  for (int idx = i0; idx < G4 * 1024; idx += stride) {
    int n = idx >> 10, k = idx & 1023;
    float v = (k < 512) ? Wih1[n * 512 + k] : Whh1[n * 512 + (k - 512)];
    W1p[idx] = (u16)f2bf(v);
  }
}

__global__ void prep_xe(const float* __restrict__ xf, const float* __restrict__ z,
                        const float* __restrict__ Wz, const float* __restrict__ bz,
                        u16* __restrict__ xe) {
  int idx = blockIdx.x * blockDim.x + threadIdx.x;
  if (idx >= NSTEPS * B_SZ) return;
  int t = idx >> 10, b = idx & 1023;
  float zb[9];
#pragma unroll
  for (int i = 0; i < 9; i++) {
    float s = bz[i];
#pragma unroll
    for (int d = 0; d < 16; d++) s += z[b * 16 + d] * Wz[i * 16 + d];
    zb[i] = s;
  }
  __align__(16) u16 o[16];
  o[0] = (u16)f2bf(zb[0]);
#pragma unroll
  for (int e = 0; e < 8; e++) o[1 + e] = (u16)f2bf(xf[b * 512 + t * 8 + e] + zb[1 + e]);
#pragma unroll
  for (int k = 9; k < 16; k++) o[k] = 0;
  uint4* dst = (uint4*)(xe + (size_t)idx * 16);
  dst[0] = *(const uint4*)&o[0];
  dst[1] = *(const uint4*)&o[8];
}

__global__ void prep_state(const float* __restrict__ h0in, u16* __restrict__ h0s,
                           u16* __restrict__ h1s, u32* __restrict__ flags) {
  int i = blockIdx.x * blockDim.x + threadIdx.x;
  if (i < B_SZ * H_SZ) {
    h0s[524288 + i] = (u16)f2bf(h0in[i]);
    h1s[524288 + i] = (u16)f2bf(h0in[524288 + i]);
  }
  if (i < 256) flags[i] = 0;
}

// ---------------- main persistent kernel ----------------
struct MainParams {
  const float* y0; const float* c0;
  const float* bih0; const float* bhh0; const float* bih1; const float* bhh1;
  const float* wproj; const float* bproj;
  const u16* xe; const u16* W0p; const u16* W1p;
  u64* h0u; u64* h1u; float* ypart; u32* flags; float* out;
};

__device__ __forceinline__ f4 MFMA_(s8 a, s8 b, f4 c) {
  return __builtin_amdgcn_mfma_f32_16x16x32_bf16(a, b, c, 0, 0, 0);
}

// prologue only (one-time): K=512 gemm with intrinsic atomic loads
__device__ __forceinline__ void gemmK512_2(const u64* hb, int au0, int au1,
    const char* b0p, const char* b1p, f4 acc[4]) {
#pragma unroll
  for (int kc = 0; kc < 16; kc++) {
    uab a0; a0.q[0] = ald(hb + au0 + kc * 8); a0.q[1] = ald(hb + au0 + kc * 8 + 1);
    uab a1; a1.q[0] = ald(hb + au1 + kc * 8); a1.q[1] = ald(hb + au1 + kc * 8 + 1);
    s8 b0 = *(const s8*)(b0p + kc * 64);
    s8 b1 = *(const s8*)(b1p + kc * 64);
    acc[0] = MFMA_(a0.v, b0, acc[0]);
    acc[1] = MFMA_(a0.v, b1, acc[1]);
    acc[2] = MFMA_(a1.v, b0, acc[2]);
    acc[3] = MFMA_(a1.v, b1, acc[3]);
  }
}

// consume 8 loaded regs (4 k-chunks x 2 rows) into two acc sets
__device__ __forceinline__ void cons_dual8(
    v4 A0, v4 A1, v4 A2, v4 A3, v4 A4, v4 A5, v4 A6, v4 A7,
    const char* w10, const char* w11, const char* w00, const char* w01,
    f4 acc1[4], f4 acc0[4]) {
#define DPAIR(x, y, OFF) do { \
    s8 b10 = *(const s8*)(w10 + OFF); s8 b11 = *(const s8*)(w11 + OFF); \
    s8 b00 = *(const s8*)(w00 + OFF); s8 b01 = *(const s8*)(w01 + OFF); \
    acc1[0] = MFMA_(x, b10, acc1[0]); acc1[1] = MFMA_(x, b11, acc1[1]); \
    acc1[2] = MFMA_(y, b10, acc1[2]); acc1[3] = MFMA_(y, b11, acc1[3]); \
    acc0[0] = MFMA_(x, b00, acc0[0]); acc0[1] = MFMA_(x, b01, acc0[1]); \
    acc0[2] = MFMA_(y, b00, acc0[2]); acc0[3] = MFMA_(y, b01, acc0[3]); } while (0)
  DPAIR(as_s8(A0), as_s8(A1), 0);
  DPAIR(as_s8(A2), as_s8(A3), 64);
  DPAIR(as_s8(A4), as_s8(A5), 128);
  DPAIR(as_s8(A6), as_s8(A7), 192);
#undef DPAIR
}

// consume 8 loaded regs into one acc set
__device__ __forceinline__ void cons_sing8(
    v4 A0, v4 A1, v4 A2, v4 A3, v4 A4, v4 A5, v4 A6, v4 A7,
    const char* w0, const char* w1, f4 acc[4]) {
#define SPAIR(x, y, OFF) do { \
    s8 b0 = *(const s8*)(w0 + OFF); s8 b1 = *(const s8*)(w1 + OFF); \
    acc[0] = MFMA_(x, b0, acc[0]); acc[1] = MFMA_(x, b1, acc[1]); \
    acc[2] = MFMA_(y, b0, acc[2]); acc[3] = MFMA_(y, b1, acc[3]); } while (0)
  SPAIR(as_s8(A0), as_s8(A1), 0);
  SPAIR(as_s8(A2), as_s8(A3), 64);
  SPAIR(as_s8(A4), as_s8(A5), 128);
  SPAIR(as_s8(A6), as_s8(A7), 192);
#undef SPAIR
}

// arrival: per-wave vmcnt drain -> one relaxed flag store -> 1-wave poll of 64 slots
__device__ __forceinline__ void barrier_wait(u32* slots, int js, int tid, u32 target) {
  asm volatile("s_waitcnt vmcnt(0)" ::: "memory");
  __syncthreads();
  if (tid == 0) ast32(&slots[js], target);
  if (tid < 64) {
    int spins = 0;
    while (ald32(&slots[tid]) < target) {
      __builtin_amdgcn_s_sleep(1);
      if (++spins > (1 << 18)) break;   // fail-safe: never hang
    }
  }
  __syncthreads();
}

struct LaneCtx { int mb0, grp, pp, jl, hlf; };

// bias, lane^8 gate exchange (i,g <-> f,o), cell math, write h (bf16) to LDS stage
__device__ __forceinline__ void cell_update(f4 acc[4], const float bias[2], float cr[2][2],
    u16* __restrict__ hst, int lbase, const LaneCtx& L, float hval[2][2]) {
#pragma unroll
  for (int m = 0; m < 2; m++)
#pragma unroll
    for (int n = 0; n < 2; n++)
#pragma unroll
      for (int r = 0; r < 4; r++) acc[m * 2 + n][r] += bias[n];
  f4 rx[4];
#pragma unroll
  for (int q = 0; q < 4; q++)
#pragma unroll
    for (int r = 0; r < 4; r++) rx[q][r] = __shfl_xor(acc[q][r], 8);
#pragma unroll
  for (int mtl = 0; mtl < 2; mtl++) {
#pragma unroll
    for (int q = 0; q < 2; q++) {
      int r = L.hlf * 2 + q;
      float iv = L.hlf ? rx[mtl * 2 + 0][r] : acc[mtl * 2 + 0][r];
      float fv = L.hlf ? acc[mtl * 2 + 0][r] : rx[mtl * 2 + 0][r];
      float gv = L.hlf ? rx[mtl * 2 + 1][r] : acc[mtl * 2 + 1][r];
      float ov = L.hlf ? acc[mtl * 2 + 1][r] : rx[mtl * 2 + 1][r];
      float c2 = sigm(fv) * cr[mtl][q] + sigm(iv) * tanh_(gv);
      float hv = sigm(ov) * tanh_(c2);
      cr[mtl][q] = c2;
      hval[mtl][q] = hv;
      int lrow = lbase + mtl * 16 + L.grp * 4 + r;
      hst[lrow * 8 + L.jl] = (u16)f2bf(hv);
    }
  }
}

__global__ __launch_bounds__(512, 2) void lstm_main(MainParams p) {
  extern __shared__ char lds[];
  char* ldsW0 = lds;
  char* ldsW1 = lds + LDS_W1_OFF;
  float* yrow = (float*)(lds + LDS_YROW_OFF);
  u16* hst = (u16*)(lds + LDS_HST_OFF);
  float* psum = (float*)(lds + LDS_PSUM_OFF);

  const int bx = blockIdx.x, chunk = bx >> 6, js = bx & 63;
  const int tid = threadIdx.x, lane = tid & 63, wid = tid >> 6;

  { // stage weight slices into LDS once
    int n = tid & 31, part = tid >> 5;
    int ng = ((n >> 3) << 9) + js * 8 + (n & 7);
    const u32* s0 = (const u32*)(p.W0p + (size_t)ng * 544);
    u32* d0 = (u32*)(ldsW0 + n * LDS_W0_STRIDE);
#pragma unroll
    for (int q = 0; q < 17; q++) d0[part * 17 + q] = s0[part * 17 + q];
    const u32* s1 = (const u32*)(p.W1p + (size_t)ng * 1024);
    u32* d1 = (u32*)(ldsW1 + n * LDS_W1_STRIDE);
#pragma unroll
    for (int q = 0; q < 32; q++) d1[part * 32 + q] = s1[part * 32 + q];
  }

  LaneCtx L;
  L.grp = lane >> 4; L.pp = lane & 15; L.jl = lane & 7; L.hlf = (lane >> 3) & 1;
  L.mb0 = chunk * 256 + wid * 32;
  const int lbase = wid * 32;
  const int j = js * 8 + L.jl;
  const int arow0 = L.mb0 + L.pp, arow1 = L.mb0 + 16 + L.pp;
  const int aoff0 = arow0 * 1024 + L.grp * 16;   // byte offset in [1024][512] bf16
  const int aoff1 = arow1 * 1024 + L.grp * 16;
  const int au0 = arow0 * 128 + L.grp * 2;       // u64 index (prologue)
  const int au1 = arow1 * 128 + L.grp * 2;

  float bias0[2], bias1[2];
#pragma unroll
  for (int ntl = 0; ntl < 2; ntl++) {
    int n = ntl * 16 + L.pp;
    int ng = ((n >> 3) << 9) + js * 8 + (n & 7);
    bias0[ntl] = p.bih0[ng] + p.bhh0[ng];
    bias1[ntl] = p.bih1[ng] + p.bhh1[ng];
  }
  float wpj = p.wproj[j];
  float bpj = p.bproj[0];

  float c0r[2][2], c1r[2][2];
#pragma unroll
  for (int mtl = 0; mtl < 2; mtl++)
#pragma unroll
    for (int q = 0; q < 2; q++) {
      int row = L.mb0 + mtl * 16 + L.grp * 4 + L.hlf * 2 + q;
      c0r[mtl][q] = p.c0[row * 512 + j];
      c1r[mtl][q] = p.c0[524288 + row * 512 + j];
    }

  u32* flagc = p.flags + chunk * 64;
  const char* wb00 = ldsW0 + L.pp * LDS_W0_STRIDE + L.grp * 16;
  const char* wb01 = ldsW0 + (16 + L.pp) * LDS_W0_STRIDE + L.grp * 16;
  const char* wb10 = ldsW1 + L.pp * LDS_W1_STRIDE + L.grp * 16;
  const char* wb11 = ldsW1 + (16 + L.pp) * LDS_W1_STRIDE + L.grp * 16;

  __syncthreads();

  // prologue: layer-0 h-part for t=0 from initial h0 (buffer 1)
  f4 acc0c[4] = {{0,0,0,0},{0,0,0,0},{0,0,0,0},{0,0,0,0}};
  gemmK512_2(p.h0u + 131072, au0, au1, wb00 + 64, wb01 + 64, acc0c);

  for (int t = 0; t < NSTEPS; t++) {
    // ============ phase 1: y-reduce + rank-32 input gemm + cell0 ============
    if (t > 0) {
      // all 512 threads: half-row partial sums of ypart
      int r = tid & 255, half = tid >> 8;
      const char* yp = (const char*)p.ypart + (size_t)(chunk * 256 + r) * 256 + half * 128;
      v4 y0, y1, y2, y3, y4, y5, y6, y7;
      LOADX4(y0, yp, 0);  LOADX4(y1, yp, 16); LOADX4(y2, yp, 32);  LOADX4(y3, yp, 48);
      LOADX4(y4, yp, 64); LOADX4(y5, yp, 80); LOADX4(y6, yp, 96);  LOADX4(y7, yp, 112);
      WAITV(0);
      float s = 0.f;
#define YACC(v_) do { vf4 w; w.u = v_; s += (w.f[0] + w.f[1]) + (w.f[2] + w.f[3]); } while (0)
      YACC(y0); YACC(y1); YACC(y2); YACC(y3); YACC(y4); YACC(y5); YACC(y6); YACC(y7);
#undef YACC
      psum[tid] = s;
    }
    __syncthreads();
    if (tid < 256) {
      int row = chunk * 256 + tid;
      float y;
      if (t == 0) y = p.y0[row];
      else {
        y = psum[tid] + psum[tid + 256] + bpj;
        if (js == 0) p.out[row * 64 + (t - 1)] = y;
      }
      yrow[tid] = y;
    }
    __syncthreads();

    { // K-chunk 0 of layer 0: [prev_y, exo]+z_bias (K padded to 32)
      s8 a0 = {0,0,0,0,0,0,0,0}, a1 = {0,0,0,0,0,0,0,0};
      if (L.grp < 2) {
        const char* xb = (const char*)p.xe + (size_t)t * 32768;
        a0 = *(const s8*)(xb + arow0 * 32 + L.grp * 16);
        a1 = *(const s8*)(xb + arow1 * 32 + L.grp * 16);
        if (L.grp == 0) {
          float ya = yrow[wid * 32 + L.pp];
          float yb = yrow[wid * 32 + 16 + L.pp];
          a0[0] = f2bf(bf2f(a0[0]) + ya);
          a1[0] = f2bf(bf2f(a1[0]) + yb);
        }
      }
      s8 b0 = *(const s8*)(wb00);
      s8 b1 = *(const s8*)(wb01);
      acc0c[0] = MFMA_(a0, b0, acc0c[0]);
      acc0c[1] = MFMA_(a0, b1, acc0c[1]);
      acc0c[2] = MFMA_(a1, b0, acc0c[2]);
      acc0c[3] = MFMA_(a1, b1, acc0c[3]);
    }
    float hdum[2][2];
    cell_update(acc0c, bias0, c0r, hst, lbase, L, hdum);
    __syncthreads();
    {
      u64* h0cur = p.h0u + (size_t)(t & 1) * 131072;
      if (tid < 256) {
        const u64* src = (const u64*)&hst[tid * 8];
        u64* dst = h0cur + (chunk * 256 + tid) * 128 + js * 2;
        ast(dst, src[0]);
        ast(dst + 1, src[1]);
      }
    }
    barrier_wait(flagc, js, tid, (u32)(2 * t + 1));

    // ============ phase 2: layer1 + next-step layer0 h-part, 2-group pipeline ============
    {
      const char* h0b = (const char*)(p.h0u + (size_t)(t & 1) * 131072);
      const char* h1b = (const char*)(p.h1u + (size_t)((t + 1) & 1) * 131072);
      const char* p00 = h0b + aoff0; const char* p01 = h0b + aoff1;
      const char* p10 = h1b + aoff0; const char* p11 = h1b + aoff1;

      f4 acc1[4] = {{0,0,0,0},{0,0,0,0},{0,0,0,0},{0,0,0,0}};
#pragma unroll
      for (int q = 0; q < 4; q++) acc0c[q] = (f4){0, 0, 0, 0};

      v4 A0, A1, A2, A3, A4, A5, A6, A7;   // group A (named scalars: no arrays near asm)
      v4 C0, C1, C2, C3, C4, C5, C6, C7;   // group B

      IS8(A0,A1,A2,A3,A4,A5,A6,A7, p00, p01, 0, 64, 128, 192);       // h0 g0
      IS8(C0,C1,C2,C3,C4,C5,C6,C7, p00, p01, 256, 320, 384, 448);    // h0 g1
      WAITV(8);
      cons_dual8(A0,A1,A2,A3,A4,A5,A6,A7, wb10, wb11, wb00 + 64, wb01 + 64, acc1, acc0c);
      IS8(A0,A1,A2,A3,A4,A5,A6,A7, p00, p01, 512, 576, 640, 704);    // h0 g2
      WAITV(8);
      cons_dual8(C0,C1,C2,C3,C4,C5,C6,C7, wb10 + 256, wb11 + 256, wb00 + 320, wb01 + 320, acc1, acc0c);
      IS8(C0,C1,C2,C3,C4,C5,C6,C7, p00, p01, 768, 832, 896, 960);    // h0 g3
      WAITV(8);
      cons_dual8(A0,A1,A2,A3,A4,A5,A6,A7, wb10 + 512, wb11 + 512, wb00 + 576, wb01 + 576, acc1, acc0c);
      IS8(A0,A1,A2,A3,A4,A5,A6,A7, p10, p11, 0, 64, 128, 192);       // h1 g0
      WAITV(8);
      cons_dual8(C0,C1,C2,C3,C4,C5,C6,C7, wb10 + 768, wb11 + 768, wb00 + 832, wb01 + 832, acc1, acc0c);
      IS8(C0,C1,C2,C3,C4,C5,C6,C7, p10, p11, 256, 320, 384, 448);    // h1 g1
      WAITV(8);
      cons_sing8(A0,A1,A2,A3,A4,A5,A6,A7, wb10 + 1024, wb11 + 1024, acc1);
      IS8(A0,A1,A2,A3,A4,A5,A6,A7, p10, p11, 512, 576, 640, 704);    // h1 g2
      WAITV(8);
      cons_sing8(C0,C1,C2,C3,C4,C5,C6,C7, wb10 + 1280, wb11 + 1280, acc1);
      IS8(C0,C1,C2,C3,C4,C5,C6,C7, p10, p11, 768, 832, 896, 960);    // h1 g3
      WAITV(8);
      cons_sing8(A0,A1,A2,A3,A4,A5,A6,A7, wb10 + 1536, wb11 + 1536, acc1);
      WAITV(0);
      cons_sing8(C0,C1,C2,C3,C4,C5,C6,C7, wb10 + 1792, wb11 + 1792, acc1);

      float hval[2][2];
      cell_update(acc1, bias1, c1r, hst, lbase, L, hval);

      // proj partials over this block's 8 j's
#pragma unroll
      for (int mtl = 0; mtl < 2; mtl++)
#pragma unroll
        for (int q = 0; q < 2; q++) {
          float s = hval[mtl][q] * wpj;
          s += __shfl_xor(s, 1);
          s += __shfl_xor(s, 2);
          s += __shfl_xor(s, 4);
          if (L.jl == 0) {
            int row = L.mb0 + mtl * 16 + L.grp * 4 + L.hlf * 2 + q;
            ast32((u32*)&p.ypart[row * 64 + js], __float_as_uint(s));
          }
        }
      __syncthreads();
      u64* h1cur = p.h1u + (size_t)(t & 1) * 131072;
      if (tid < 256) {
        const u64* src = (const u64*)&hst[tid * 8];
        u64* dst = h1cur + (chunk * 256 + tid) * 128 + js * 2;
        ast(dst, src[0]);
        ast(dst + 1, src[1]);
      }
    }
    barrier_wait(flagc, js, tid, (u32)(2 * t + 2));
  }

  // final step's yhat
  if (js == 0 && tid < 256) {
    int row = chunk * 256 + tid;
    float s = bpj;
    const u64* yp = (const u64*)(p.ypart + row * 64);
#pragma unroll
    for (int q = 0; q < 32; q++) { uf2 w; w.q = ald(yp + q); s += w.f[0] + w.f[1]; }
    p.out[row * 64 + 63] = s;
  }
}

extern "C" void kernel_launch(void* const* d_in, const int* in_sizes, int n_in,
                              void* d_out, int out_size, void* d_ws, size_t ws_size,
                              hipStream_t stream) {
  const float* y0   = (const float*)d_in[0];
  const float* xf   = (const float*)d_in[1];
  const float* h0   = (const float*)d_in[2];
  const float* c0   = (const float*)d_in[3];
  const float* z    = (const float*)d_in[4];
  const float* Wih0 = (const float*)d_in[5];
  const float* Whh0 = (const float*)d_in[6];
  const float* bih0 = (const float*)d_in[7];
  const float* bhh0 = (const float*)d_in[8];
  const float* Wih1 = (const float*)d_in[9];
  const float* Whh1 = (const float*)d_in[10];
  const float* bih1 = (const float*)d_in[11];
  const float* bhh1 = (const float*)d_in[12];
  const float* Wpr  = (const float*)d_in[13];
  const float* bpr  = (const float*)d_in[14];
  const float* Wz   = (const float*)d_in[15];
  const float* bz   = (const float*)d_in[16];

  if (ws_size < WS_NEEDED) return;
  char* ws = (char*)d_ws;
  u16* xe    = (u16*)(ws + WS_XE);
  u16* W0p   = (u16*)(ws + WS_W0P);
  u16* W1p   = (u16*)(ws + WS_W1P);
  u64* h0u   = (u64*)(ws + WS_H0S);
  u64* h1u   = (u64*)(ws + WS_H1S);
  float* ypart = (float*)(ws + WS_YPART);
  u32* flags = (u32*)(ws + WS_FLAGS);

  prep_pack<<<1024, 256, 0, stream>>>(Wih0, Whh0, Wih1, Whh1, W0p, W1p);
  prep_xe<<<256, 256, 0, stream>>>(xf, z, Wz, bz, xe);
  prep_state<<<2048, 256, 0, stream>>>(h0, (u16*)h0u, (u16*)h1u, flags);

  MainParams prm;
  prm.y0 = y0; prm.c0 = c0;
  prm.bih0 = bih0; prm.bhh0 = bhh0; prm.bih1 = bih1; prm.bhh1 = bhh1;
  prm.wproj = Wpr; prm.bproj = bpr;
  prm.xe = xe; prm.W0p = W0p; prm.W1p = W1p;
  prm.h0u = h0u; prm.h1u = h1u; prm.ypart = ypart; prm.flags = flags;
  prm.out = (float*)d_out;

  hipFuncSetAttribute((const void*)lstm_main, hipFuncAttributeMaxDynamicSharedMemorySize, LDS_TOTAL);
  void* args[] = { &prm };
  hipLaunchCooperativeKernel((void*)lstm_main, dim3(256), dim3(512), args, LDS_TOTAL, stream);
}